// Round 2
// baseline (766.598 us; speedup 1.0000x reference)
//
#include <hip/hip_runtime.h>

// pred: (N=8, V=3, C=24, T=8, H=128, W=128) f32 -> 75,497,472 elems
// mask: (8,128,128) int32 -> 131,072 elems
// vq:   (1,24) f32
// out = sum(|pred - vq[c]|*w) / sum_over_pred_grid(w),  w = 1-mask[n,h,w]
// (sum of w over the full pred grid == V*C*T * sum over mask, so no VCT factor)

#define HW        16384u      // H*W
#define PER_N     9437184u    // V*C*T*H*W
#define CDIM      24u
#define NELEM     75497472u
#define N4        18874368u   // NELEM / 4
#define NBLOCKS   8192u

__device__ __forceinline__ float2 block_reduce2_256(float a, float b) {
    #pragma unroll
    for (int o = 32; o > 0; o >>= 1) {
        a += __shfl_down(a, o, 64);
        b += __shfl_down(b, o, 64);
    }
    __shared__ float sa[4], sb[4];
    const int lane = threadIdx.x & 63;
    const int wid  = threadIdx.x >> 6;
    if (lane == 0) { sa[wid] = a; sb[wid] = b; }
    __syncthreads();
    float2 r = make_float2(0.f, 0.f);
    if (threadIdx.x == 0) {
        r.x = sa[0] + sa[1] + sa[2] + sa[3];
        r.y = sb[0] + sb[1] + sb[2] + sb[3];
    }
    return r;
}

// ws layout: ws[0] = num (f32), ws[1] = wsum (f32), ws[2] = done counter (u32)
__global__ void __launch_bounds__(256) fused_kernel(
        const float4* __restrict__ pred4,
        const int*    __restrict__ mask,
        const float*  __restrict__ vq,
        float* __restrict__ ws,
        float* __restrict__ out) {
    unsigned idx = blockIdx.x * blockDim.x + threadIdx.x;
    const unsigned stride = NBLOCKS * 256u;
    float acc_n = 0.0f, acc_w = 0.0f;
    for (unsigned j = idx; j < N4; j += stride) {
        unsigned e  = j << 2;            // flat element index of first of 4
        unsigned n  = e / PER_N;         // constant divisor -> magic mul
        unsigned hw = e & (HW - 1u);
        unsigned c  = (e >> 17) % CDIM;  // (e / (T*H*W)) % C
        float4 p = pred4[j];
        int4 m = *(const int4*)(mask + n * HW + hw);
        float v = vq[c];
        float w0 = (float)(1 - m.x), w1 = (float)(1 - m.y);
        float w2 = (float)(1 - m.z), w3 = (float)(1 - m.w);
        acc_n += fabsf(p.x - v) * w0 + fabsf(p.y - v) * w1
               + fabsf(p.z - v) * w2 + fabsf(p.w - v) * w3;
        acc_w += w0 + w1 + w2 + w3;
    }
    float2 t = block_reduce2_256(acc_n, acc_w);
    if (threadIdx.x == 0) {
        atomicAdd(&ws[0], t.x);
        atomicAdd(&ws[1], t.y);
        __threadfence();
        unsigned old = atomicAdd((unsigned*)&ws[2], 1u);
        if (old == NBLOCKS - 1u) {
            // last block: read totals with device-scope atomics (cross-XCD safe)
            float num  = atomicAdd(&ws[0], 0.0f);
            float wsum = atomicAdd(&ws[1], 0.0f);
            out[0] = num / wsum;
        }
    }
}

extern "C" void kernel_launch(void* const* d_in, const int* in_sizes, int n_in,
                              void* d_out, int out_size, void* d_ws, size_t ws_size,
                              hipStream_t stream) {
    const float* pred = (const float*)d_in[0];
    const int*   mask = (const int*)d_in[1];
    const float* vq   = (const float*)d_in[2];
    float* ws  = (float*)d_ws;
    float* out = (float*)d_out;

    hipMemsetAsync(d_ws, 0, 3 * sizeof(float), stream);
    fused_kernel<<<NBLOCKS, 256, 0, stream>>>((const float4*)pred, mask, vq, ws, out);
}

// Round 3
// 396.799 us; speedup vs baseline: 1.9320x; 1.9320x over previous
//
#include <hip/hip_runtime.h>

// pred: (N=8, V=3, C=24, T=8, H=128, W=128) f32 -> 75,497,472 elems
// mask: (8,128,128) int32 -> 131,072 elems
// vq:   (1,24) f32
// out = sum(|pred - vq[c]|*w) / sum_over_pred_grid(w),  w = 1-mask[n,h,w]
// (sum of w over full pred grid == V*C*T * sum over mask grid, so no VCT factor)
//
// R2 post-mortem: 8192 blocks x 3 device-scope atomics + __threadfence on ONE
// cache line serialized (~482us). Fix: per-block float2 partial stores to
// private d_ws slots (no atomics, no fence), then a 1-block reduce kernel.

#define HW        16384u      // H*W
#define PER_N     9437184u    // V*C*T*H*W
#define CDIM      24u
#define N4        18874368u   // 75497472 / 4
#define NBLOCKS   8192u       // 8192*256 threads * 9 iters * 4 elems = exact cover

__global__ void __launch_bounds__(256) partial_kernel(
        const float4* __restrict__ pred4,
        const int*    __restrict__ mask,
        const float*  __restrict__ vq,
        float2* __restrict__ partials) {
    unsigned idx = blockIdx.x * 256u + threadIdx.x;
    const unsigned stride = NBLOCKS * 256u;
    float acc_n = 0.0f, acc_w = 0.0f;
    #pragma unroll 3
    for (unsigned j = idx; j < N4; j += stride) {
        unsigned e  = j << 2;            // flat element index of first of 4
        unsigned n  = e / PER_N;         // constant divisor -> magic mul
        unsigned hw = e & (HW - 1u);
        unsigned c  = (e >> 17) % CDIM;  // (e / (T*H*W)) % C
        float4 p = pred4[j];
        int4 m = *(const int4*)(mask + n * HW + hw);
        float v = vq[c];
        float w0 = (float)(1 - m.x), w1 = (float)(1 - m.y);
        float w2 = (float)(1 - m.z), w3 = (float)(1 - m.w);
        acc_n += fabsf(p.x - v) * w0 + fabsf(p.y - v) * w1
               + fabsf(p.z - v) * w2 + fabsf(p.w - v) * w3;
        acc_w += w0 + w1 + w2 + w3;
    }
    // block reduce (4 waves)
    #pragma unroll
    for (int o = 32; o > 0; o >>= 1) {
        acc_n += __shfl_down(acc_n, o, 64);
        acc_w += __shfl_down(acc_w, o, 64);
    }
    __shared__ float sa[4], sb[4];
    const int lane = threadIdx.x & 63;
    const int wid  = threadIdx.x >> 6;
    if (lane == 0) { sa[wid] = acc_n; sb[wid] = acc_w; }
    __syncthreads();
    if (threadIdx.x == 0) {
        partials[blockIdx.x] = make_float2(sa[0] + sa[1] + sa[2] + sa[3],
                                           sb[0] + sb[1] + sb[2] + sb[3]);
    }
}

__global__ void __launch_bounds__(1024) reduce_kernel(
        const float2* __restrict__ partials, float* __restrict__ out) {
    float acc_n = 0.0f, acc_w = 0.0f;
    #pragma unroll
    for (unsigned i = 0; i < NBLOCKS / 1024u; ++i) {
        float2 p = partials[threadIdx.x + i * 1024u];
        acc_n += p.x;
        acc_w += p.y;
    }
    #pragma unroll
    for (int o = 32; o > 0; o >>= 1) {
        acc_n += __shfl_down(acc_n, o, 64);
        acc_w += __shfl_down(acc_w, o, 64);
    }
    __shared__ float sa[16], sb[16];
    const int lane = threadIdx.x & 63;
    const int wid  = threadIdx.x >> 6;
    if (lane == 0) { sa[wid] = acc_n; sb[wid] = acc_w; }
    __syncthreads();
    if (threadIdx.x == 0) {
        float n = 0.0f, w = 0.0f;
        #pragma unroll
        for (int i = 0; i < 16; ++i) { n += sa[i]; w += sb[i]; }
        out[0] = n / w;
    }
}

extern "C" void kernel_launch(void* const* d_in, const int* in_sizes, int n_in,
                              void* d_out, int out_size, void* d_ws, size_t ws_size,
                              hipStream_t stream) {
    const float* pred = (const float*)d_in[0];
    const int*   mask = (const int*)d_in[1];
    const float* vq   = (const float*)d_in[2];
    float2* partials = (float2*)d_ws;   // 8192 * 8 B = 64 KB, all slots written
    float*  out      = (float*)d_out;

    partial_kernel<<<NBLOCKS, 256, 0, stream>>>((const float4*)pred, mask, vq, partials);
    reduce_kernel<<<1, 1024, 0, stream>>>(partials, out);
}

// Round 4
// 394.278 us; speedup vs baseline: 1.9443x; 1.0064x over previous
//
#include <hip/hip_runtime.h>

// pred: (N=8, V=3, C=24, T=8, H=128, W=128) f32 -> 75,497,472 elems
// mask: (8,128,128) int32; vq: (1,24) f32
// out = sum(|pred - vq[c]|*w) / sum_over_pred_grid(w),  w = 1-mask[n,h,w]
//
// R2: contended device atomics = 482us. R3: per-block partial stores = fast.
// R4: fully unroll the exactly-9-iteration grid-stride loop. stride*4 = 2^23,
// so hw is loop-invariant and n/c fold to affine fns of k; 9 loads in flight.

#define HW        16384u      // H*W
#define PER_N     9437184u    // V*C*T*H*W
#define CDIM      24u
#define N4        18874368u   // 75497472 / 4
#define NBLOCKS   8192u
#define STRIDE    2097152u    // NBLOCKS*256; 9 iters exact: STRIDE*9 == N4

__global__ void __launch_bounds__(256) partial_kernel(
        const float4* __restrict__ pred4,
        const int*    __restrict__ mask,
        const float*  __restrict__ vq,
        float2* __restrict__ partials) {
    const unsigned idx = blockIdx.x * 256u + threadIdx.x;
    const unsigned e0  = idx << 2;           // 4*idx < 2^23
    const unsigned hw  = e0 & (HW - 1u);     // loop-invariant: stride*4 = 2^23
    float acc_n = 0.0f, acc_w = 0.0f;
    #pragma unroll
    for (unsigned k = 0; k < 9u; ++k) {
        const unsigned j = idx + k * STRIDE;
        const unsigned e = e0 + (k << 23);   // flat element index
        const unsigned n = e / PER_N;        // const-divisor, k const -> cheap
        const unsigned c = (e >> 17) % CDIM;
        float4 p = pred4[j];
        int4 m = *(const int4*)(mask + n * HW + hw);
        float v = vq[c];
        float w0 = (float)(1 - m.x), w1 = (float)(1 - m.y);
        float w2 = (float)(1 - m.z), w3 = (float)(1 - m.w);
        acc_n += fabsf(p.x - v) * w0 + fabsf(p.y - v) * w1
               + fabsf(p.z - v) * w2 + fabsf(p.w - v) * w3;
        acc_w += w0 + w1 + w2 + w3;
    }
    // block reduce (4 waves)
    #pragma unroll
    for (int o = 32; o > 0; o >>= 1) {
        acc_n += __shfl_down(acc_n, o, 64);
        acc_w += __shfl_down(acc_w, o, 64);
    }
    __shared__ float sa[4], sb[4];
    const int lane = threadIdx.x & 63;
    const int wid  = threadIdx.x >> 6;
    if (lane == 0) { sa[wid] = acc_n; sb[wid] = acc_w; }
    __syncthreads();
    if (threadIdx.x == 0) {
        partials[blockIdx.x] = make_float2(sa[0] + sa[1] + sa[2] + sa[3],
                                           sb[0] + sb[1] + sb[2] + sb[3]);
    }
}

__global__ void __launch_bounds__(1024) reduce_kernel(
        const float2* __restrict__ partials, float* __restrict__ out) {
    float acc_n = 0.0f, acc_w = 0.0f;
    #pragma unroll
    for (unsigned i = 0; i < NBLOCKS / 1024u; ++i) {
        float2 p = partials[threadIdx.x + i * 1024u];
        acc_n += p.x;
        acc_w += p.y;
    }
    #pragma unroll
    for (int o = 32; o > 0; o >>= 1) {
        acc_n += __shfl_down(acc_n, o, 64);
        acc_w += __shfl_down(acc_w, o, 64);
    }
    __shared__ float sa[16], sb[16];
    const int lane = threadIdx.x & 63;
    const int wid  = threadIdx.x >> 6;
    if (lane == 0) { sa[wid] = acc_n; sb[wid] = acc_w; }
    __syncthreads();
    if (threadIdx.x == 0) {
        float n = 0.0f, w = 0.0f;
        #pragma unroll
        for (int i = 0; i < 16; ++i) { n += sa[i]; w += sb[i]; }
        out[0] = n / w;
    }
}

extern "C" void kernel_launch(void* const* d_in, const int* in_sizes, int n_in,
                              void* d_out, int out_size, void* d_ws, size_t ws_size,
                              hipStream_t stream) {
    const float* pred = (const float*)d_in[0];
    const int*   mask = (const int*)d_in[1];
    const float* vq   = (const float*)d_in[2];
    float2* partials = (float2*)d_ws;   // 8192 * 8 B, all slots written
    float*  out      = (float*)d_out;

    partial_kernel<<<NBLOCKS, 256, 0, stream>>>((const float4*)pred, mask, vq, partials);
    reduce_kernel<<<1, 1024, 0, stream>>>(partials, out);
}

// Round 5
// 389.159 us; speedup vs baseline: 1.9699x; 1.0132x over previous
//
#include <hip/hip_runtime.h>

// pred: (N=8, V=3, C=24, T=8, H=128, W=128) f32 -> 75,497,472 elems
// mask: (8,128,128) int32; vq: (1,24) f32
// out = sum(|pred - vq[c]|*w) / sum_over_pred_grid(w),  w = 1-mask[n,h,w]
//
// R2: contended device atomics = 482us (removed). R4: full unroll = neutral.
// R5: t-major per-thread assignment. Each thread owns (n,v,c,hw4) and loops
// k=0..7 over t (element stride H*W). n, c, and the mask word are then
// loop-invariant: 1 mask int4 + 1 (wave-uniform, scalar) vq load + 8 pred
// float4 loads per thread -> VMEM instr count ~halved vs R4.

#define HW4       16384u      // H*W elements (float4 stride per t-step = HW/4)
#define THW       131072u     // T*H*W elems per (n,v,c)
#define CDIM      24u
#define VC        72u         // V*C
#define NTHREADS  2359296u    // 576 (n,v,c) * 4096 hw4-groups
#define NBLOCKS   9216u       // NTHREADS / 256
#define NPART     9216u

__global__ void __launch_bounds__(256) partial_kernel(
        const float4* __restrict__ pred4,
        const int*    __restrict__ mask,
        const float*  __restrict__ vq,
        float2* __restrict__ partials) {
    const unsigned i = blockIdx.x * 256u + threadIdx.x;   // [0, 2359296)
    const unsigned g = i >> 12;          // (n,v,c) index, wave-uniform, [0,576)
    const unsigned r = i & 4095u;        // hw4 group within the plane
    const unsigned n = g / VC;           // const-divisor magic mul, uniform
    const unsigned c = g % CDIM;         // uniform -> scalar vq load
    const float    v = vq[c];
    const int4     m = *(const int4*)(mask + n * HW4 + r * 4u);
    const float w0 = (float)(1 - m.x), w1 = (float)(1 - m.y);
    const float w2 = (float)(1 - m.z), w3 = (float)(1 - m.w);
    const float wsum8 = (w0 + w1 + w2 + w3) * 8.0f;       // same weights all 8 t

    const unsigned j0 = g * (THW / 4u) + r;               // float4 index base
    float acc_n = 0.0f;
    #pragma unroll
    for (unsigned k = 0; k < 8u; ++k) {
        float4 p = pred4[j0 + k * (HW4 / 4u)];
        acc_n += fabsf(p.x - v) * w0 + fabsf(p.y - v) * w1
               + fabsf(p.z - v) * w2 + fabsf(p.w - v) * w3;
    }
    float acc_w = wsum8;

    // block reduce (4 waves)
    #pragma unroll
    for (int o = 32; o > 0; o >>= 1) {
        acc_n += __shfl_down(acc_n, o, 64);
        acc_w += __shfl_down(acc_w, o, 64);
    }
    __shared__ float sa[4], sb[4];
    const int lane = threadIdx.x & 63;
    const int wid  = threadIdx.x >> 6;
    if (lane == 0) { sa[wid] = acc_n; sb[wid] = acc_w; }
    __syncthreads();
    if (threadIdx.x == 0) {
        partials[blockIdx.x] = make_float2(sa[0] + sa[1] + sa[2] + sa[3],
                                           sb[0] + sb[1] + sb[2] + sb[3]);
    }
}

__global__ void __launch_bounds__(1024) reduce_kernel(
        const float2* __restrict__ partials, float* __restrict__ out) {
    float acc_n = 0.0f, acc_w = 0.0f;
    #pragma unroll
    for (unsigned i = 0; i < NPART / 1024u; ++i) {   // 9 iters
        float2 p = partials[threadIdx.x + i * 1024u];
        acc_n += p.x;
        acc_w += p.y;
    }
    #pragma unroll
    for (int o = 32; o > 0; o >>= 1) {
        acc_n += __shfl_down(acc_n, o, 64);
        acc_w += __shfl_down(acc_w, o, 64);
    }
    __shared__ float sa[16], sb[16];
    const int lane = threadIdx.x & 63;
    const int wid  = threadIdx.x >> 6;
    if (lane == 0) { sa[wid] = acc_n; sb[wid] = acc_w; }
    __syncthreads();
    if (threadIdx.x == 0) {
        float n = 0.0f, w = 0.0f;
        #pragma unroll
        for (int i = 0; i < 16; ++i) { n += sa[i]; w += sb[i]; }
        out[0] = n / w;
    }
}

extern "C" void kernel_launch(void* const* d_in, const int* in_sizes, int n_in,
                              void* d_out, int out_size, void* d_ws, size_t ws_size,
                              hipStream_t stream) {
    const float* pred = (const float*)d_in[0];
    const int*   mask = (const int*)d_in[1];
    const float* vq   = (const float*)d_in[2];
    float2* partials = (float2*)d_ws;   // 9216 * 8 B, all slots written
    float*  out      = (float*)d_out;

    partial_kernel<<<NBLOCKS, 256, 0, stream>>>((const float4*)pred, mask, vq, partials);
    reduce_kernel<<<1, 1024, 0, stream>>>(partials, out);
}